// Round 10
// baseline (735.092 us; speedup 1.0000x reference)
//
#include <hip/hip_runtime.h>
#include <hip/hip_bf16.h>
#include <math.h>

#define B_ 128
#define N_ 2048
#define D_ 512
#define H_ 512

#define NEG_BIG (-1.0e30f)

typedef unsigned int uint;
typedef unsigned short ushort;

// ws layout (float offsets)
#define WS_INP  0
#define WS_ATT  (WS_INP + B_*H_)          // 65536
#define WS_M    (WS_ATT + B_*N_)          // +262144
#define WS_FLAG (WS_M + B_*D_)            // +65536
#define WS_BP   393280                    // 16B aligned; Bpack = 524288 ushort = 1MB
#define WS_NEED_FLOATS (WS_BP + 262144)

typedef __attribute__((ext_vector_type(4))) float  f32x4;
typedef __attribute__((ext_vector_type(8))) short  bf16x8;

union BF8 { unsigned short u[8]; bf16x8 v; };

__device__ __forceinline__ ushort f2bf(float x) {
    uint u = __float_as_uint(x);
    u = (u + 0x7fffu + ((u >> 16) & 1u)) >> 16;   // RNE; inputs finite
    return (ushort)u;
}
__device__ __forceinline__ float bf2f(ushort h) {
    return __uint_as_float(((uint)h) << 16);
}
__device__ __forceinline__ float fast_tanh(float x) {
    return 1.0f - 2.0f / (1.0f + __expf(2.0f * x));
}

// ---------------------------------------------------------------------------
// 1 wave: every uint must be 0/1 for an int32 mask; byte-bools give random bytes.
__global__ void detect_mask(const uint* __restrict__ mask_raw,
                            int* __restrict__ flag) {
    int lane = threadIdx.x;                 // 64 threads = 1 wave
    uint v = mask_raw[lane];
    unsigned long long m = __ballot(v <= 1u);
    if (lane == 0) *flag = (m == ~0ull) ? 1 : 0;
}

// ---------------------------------------------------------------------------
__global__ __launch_bounds__(256) void linear_kernel(
        const float* __restrict__ a, const float* __restrict__ W,
        const float* __restrict__ bias, float* __restrict__ out) {
    int idx = blockIdx.x * 256 + threadIdx.x;
    int b = idx >> 9;
    int h = idx & (H_ - 1);
    const float4* ar = (const float4*)(a + (size_t)b * D_);
    const float4* wr = (const float4*)(W + (size_t)h * D_);
    float acc = 0.f;
#pragma unroll 4
    for (int d = 0; d < D_ / 4; ++d) {
        float4 av = ar[d], wv = wr[d];
        acc = fmaf(av.x, wv.x, acc);
        acc = fmaf(av.y, wv.y, acc);
        acc = fmaf(av.z, wv.z, acc);
        acc = fmaf(av.w, wv.w, acc);
    }
    out[idx] = acc + bias[h];
}

// ---------------------------------------------------------------------------
// Pre-pack Wc into MFMA B-fragment-linear bf16 hi/lo (RNE):
// Bp[((hf*16+ks)*64 + lane)*8 + j] = bf16(Wc[hf*16+(lane&15)][ks*32+(lane>>4)*8+j])
__global__ __launch_bounds__(256) void pack_wc(const float* __restrict__ Wc,
                                               ushort* __restrict__ Bp) {
    int tid = blockIdx.x * 256 + threadIdx.x;       // 32768 threads
    int lane = tid & 63;
    int fs   = tid >> 6;
    int hf = fs >> 4, ks = fs & 15;
    int h  = hf * 16 + (lane & 15);
    int k0 = ks * 32 + (lane >> 4) * 8;
    const float* src = Wc + (size_t)h * D_ + k0;
    BF8 hi, lo;
#pragma unroll
    for (int j = 0; j < 8; ++j) {
        float x = src[j];
        hi.u[j] = f2bf(x);
        lo.u[j] = f2bf(x - bf2f(hi.u[j]));
    }
    *(bf16x8*)(Bp + (size_t)tid * 8)          = hi.v;
    *(bf16x8*)(Bp + 262144 + (size_t)tid * 8) = lo.v;
}

// ---------------------------------------------------------------------------
// Split-bf16 3-product MFMA. BM=64, 512 thr / 8 waves (2r x 4c), wave tile
// 32x128 -> acc[2][8]=64 VGPR -> launch_bounds(512,4): 4 waves/SIMD and
// 2 blocks/CU (TWO independent barrier domains: one block MFMAs while the
// other is in its CVT/stage/barrier section).
// A: reg->CVT->LDS staged (double-buffered, 16KB). B: DIRECT coalesced
// fragment loads from L2-hot Bpack (no LDS, no DMA choreography).
#define KP  32
#define NPH 16

// trunc split of 4 floats (uint view) -> 2 hi uints + 2 lo uints, stored to LDS
#define STAGE4(Ux, bi) do {                                                     \
    uint h0_ = (Ux.y & 0xFFFF0000u) | (Ux.x >> 16);                             \
    uint h1_ = (Ux.w & 0xFFFF0000u) | (Ux.z >> 16);                             \
    float r0_ = __uint_as_float(Ux.x) - __uint_as_float(Ux.x & 0xFFFF0000u);    \
    float r1_ = __uint_as_float(Ux.y) - __uint_as_float(Ux.y & 0xFFFF0000u);    \
    float r2_ = __uint_as_float(Ux.z) - __uint_as_float(Ux.z & 0xFFFF0000u);    \
    float r3_ = __uint_as_float(Ux.w) - __uint_as_float(Ux.w & 0xFFFF0000u);    \
    uint l0_ = (__float_as_uint(r1_) & 0xFFFF0000u) | (__float_as_uint(r0_) >> 16); \
    uint l1_ = (__float_as_uint(r3_) & 0xFFFF0000u) | (__float_as_uint(r2_) >> 16); \
    *(uint2*)((char*)&sAh[bi][0] + swb) = make_uint2(h0_, h1_);                 \
    *(uint2*)((char*)&sAl[bi][0] + swb) = make_uint2(l0_, l1_);                 \
} while (0)

__global__ __launch_bounds__(512, 4) void att_mfma_kernel(
        const float* __restrict__ ctx, const ushort* __restrict__ Bp,
        const float* __restrict__ bc, const float* __restrict__ V,
        const float* __restrict__ inp, float* __restrict__ att) {
    __shared__ ushort sAh[2][2048];     // 8KB [buf][frag4][lane64][8]
    __shared__ ushort sAl[2][2048];     // 8KB
    __shared__ float red[8][32];        // 1KB

    const int t    = threadIdx.x;
    const int lane = t & 63;
    const int w    = t >> 6;
    const int wr   = w >> 2;            // 32-row half
    const int wc   = w & 3;             // 128-col group
    const int g0   = blockIdx.x * 64;   // 64 flat rows per block
    const int b    = g0 >> 11;          // uniform (64 | 2048)

    // A staging: thread t -> row=t>>3, k-quad=(t&7)*4 (global coalesced: 8
    // lanes cover 128B of one row). LDS dst: fragment-linear bf16 layout.
    const int srow = t >> 3;
    const int skq  = (t & 7) * 4;
    const float* gAs = ctx + (size_t)(g0 + srow) * D_ + skq;
    const int swb = (((srow >> 4) * 64 + (srow & 15) + ((skq >> 3) << 4)) * 8
                     + (skq & 7)) * 2;  // byte offset

    // A fragment read offsets (lane-linear 16B -> conflict-free b128)
    const int ar0 = ((wr * 2 + 0) * 64 + lane) * 16;
    const int ar1 = ((wr * 2 + 1) * 64 + lane) * 16;

    // B fragment base (ushort idx): + cf*8192 + p*512
    const int bb = wc * 65536 + lane * 8;

    f32x4 acc[2][8] = {};

    // prologue: stage A(0)
    {
        uint4 U0 = *(const uint4*)(gAs);
        STAGE4(U0, 0);
    }
    __syncthreads();

    for (int p = 0; p < NPH; ++p) {
        const int buf = p & 1;
        const int pn  = (p + 1) & 15;   // uniform; last prefetch dead

        // A frags for this phase
        bf16x8 ah0 = *(const bf16x8*)((const char*)&sAh[buf][0] + ar0);
        bf16x8 al0 = *(const bf16x8*)((const char*)&sAl[buf][0] + ar0);
        bf16x8 ah1 = *(const bf16x8*)((const char*)&sAh[buf][0] + ar1);
        bf16x8 al1 = *(const bf16x8*)((const char*)&sAl[buf][0] + ar1);

        // issue next A tile load early (consumed after MFMA cluster)
        uint4 U = *(const uint4*)(gAs + pn * KP);

        __builtin_amdgcn_s_setprio(1);
#pragma unroll
        for (int cf = 0; cf < 8; ++cf) {
            const int bidx = bb + cf * 8192 + p * 512;
            bf16x8 bh = *(const bf16x8*)(Bp + bidx);            // L2-hot
            bf16x8 bl = *(const bf16x8*)(Bp + 262144 + bidx);
            acc[0][cf] = __builtin_amdgcn_mfma_f32_16x16x32_bf16(ah0, bh, acc[0][cf], 0, 0, 0);
            acc[1][cf] = __builtin_amdgcn_mfma_f32_16x16x32_bf16(ah1, bh, acc[1][cf], 0, 0, 0);
            acc[0][cf] = __builtin_amdgcn_mfma_f32_16x16x32_bf16(ah0, bl, acc[0][cf], 0, 0, 0);
            acc[1][cf] = __builtin_amdgcn_mfma_f32_16x16x32_bf16(ah1, bl, acc[1][cf], 0, 0, 0);
            acc[0][cf] = __builtin_amdgcn_mfma_f32_16x16x32_bf16(al0, bh, acc[0][cf], 0, 0, 0);
            acc[1][cf] = __builtin_amdgcn_mfma_f32_16x16x32_bf16(al1, bh, acc[1][cf], 0, 0, 0);
        }
        __builtin_amdgcn_s_setprio(0);

        STAGE4(U, buf ^ 1);             // CVT + ds_write next A
        __syncthreads();
    }

    // epilogue: tanh + V-weight + reduce over cols
    // C/D layout: col = lane&15, row = (lane>>4)*4 + j
    float P[2][4] = {};
#pragma unroll
    for (int cf = 0; cf < 8; ++cf) {
        const int h = wc * 128 + cf * 16 + (lane & 15);
        const float sh = inp[b * H_ + h] + bc[h];
        const float vh = V[h];
#pragma unroll
        for (int rf = 0; rf < 2; ++rf)
#pragma unroll
            for (int j = 0; j < 4; ++j)
                P[rf][j] += vh * fast_tanh(acc[rf][cf][j] + sh);
    }
#pragma unroll
    for (int rf = 0; rf < 2; ++rf)
#pragma unroll
        for (int j = 0; j < 4; ++j) {
            float x = P[rf][j];
            x += __shfl_xor(x, 1); x += __shfl_xor(x, 2);
            x += __shfl_xor(x, 4); x += __shfl_xor(x, 8);
            P[rf][j] = x;
        }
    if ((lane & 15) == 0) {
        const int kc = lane >> 4;
#pragma unroll
        for (int rf = 0; rf < 2; ++rf)
#pragma unroll
            for (int j = 0; j < 4; ++j)
                red[w][rf * 16 + kc * 4 + j] = P[rf][j];
    }
    __syncthreads();
    if (t < 64) {
        const int wrr = (t >> 5) * 4, r = t & 31;
        att[g0 + t] = red[wrr + 0][r] + red[wrr + 1][r] + red[wrr + 2][r] + red[wrr + 3][r];
    }
}

// ---------------------------------------------------------------------------
__global__ __launch_bounds__(256) void softmax_kernel(
        const float* __restrict__ att, const void* __restrict__ mask,
        const int* __restrict__ flag, float* __restrict__ alpha,
        float* __restrict__ logp) {
    __shared__ float row[N_];
    __shared__ float red[4];
    const int b = blockIdx.x, t = threadIdx.x;
    const int is_int = *flag;
    const int* mi = (const int*)mask;
    const unsigned char* mb = (const unsigned char*)mask;

    float lmax = -INFINITY;
    for (int n = t; n < N_; n += 256) {
        bool m = is_int ? (mi[b * N_ + n] != 0) : (mb[b * N_ + n] != 0);
        float a = m ? NEG_BIG : att[b * N_ + n];
        row[n] = a;
        lmax = fmaxf(lmax, a);
    }
#pragma unroll
    for (int off = 32; off; off >>= 1) lmax = fmaxf(lmax, __shfl_down(lmax, off));
    if ((t & 63) == 0) red[t >> 6] = lmax;
    __syncthreads();
    const float rmax = fmaxf(fmaxf(red[0], red[1]), fmaxf(red[2], red[3]));
    __syncthreads();

    float lsum = 0.f;
    for (int n = t; n < N_; n += 256) lsum += __expf(row[n] - rmax);
#pragma unroll
    for (int off = 32; off; off >>= 1) lsum += __shfl_down(lsum, off);
    if ((t & 63) == 0) red[t >> 6] = lsum;
    __syncthreads();
    const float s = red[0] + red[1] + red[2] + red[3];
    const float inv = 1.0f / s;
    const float lse = logf(s);

    for (int n = t; n < N_; n += 256) {
        float a = row[n];
        alpha[b * N_ + n] = __expf(a - rmax) * inv;
        logp[b * N_ + n]  = a - rmax - lse;
    }
}

// ---------------------------------------------------------------------------
__global__ __launch_bounds__(128) void wsum_kernel(
        const float* __restrict__ context, const float* __restrict__ alpha,
        float* __restrict__ m) {
    __shared__ float al[N_];
    const int c = blockIdx.x;
    const int b = blockIdx.y;
    const int t = threadIdx.x;
    for (int n = t; n < N_; n += 128) al[n] = alpha[(size_t)b * N_ + n];
    __syncthreads();
    const int d = c * 128 + t;
    const float* cp = context + (size_t)b * N_ * D_ + d;
    float acc = 0.f;
#pragma unroll 8
    for (int n = 0; n < N_; ++n) acc = fmaf(al[n], cp[(size_t)n * D_], acc);
    m[b * D_ + d] = acc;
}

// ---------------------------------------------------------------------------
extern "C" void kernel_launch(void* const* d_in, const int* in_sizes, int n_in,
                              void* d_out, int out_size, void* d_ws, size_t ws_size,
                              hipStream_t stream) {
    const float* x       = (const float*)d_in[0];
    const float* context = (const float*)d_in[1];
    const void*  mask    = d_in[2];
    const float* Wi      = (const float*)d_in[3];
    const float* bi      = (const float*)d_in[4];
    const float* Wc      = (const float*)d_in[5];
    const float* bc      = (const float*)d_in[6];
    const float* V       = (const float*)d_in[7];

    float* out  = (float*)d_out;
    float* ws   = (float*)d_ws;
    float* inp  = ws + WS_INP;
    float* att  = ws + WS_ATT;
    float* m    = ws + WS_M;
    int*   flag = (int*)(ws + WS_FLAG);

    float* hidden = out;
    float* alpha  = out + B_ * H_;
    float* logp   = alpha + B_ * N_;

    ushort* Bp =
        (ws_size >= (size_t)WS_NEED_FLOATS * 4) ? (ushort*)(ws + WS_BP)
                                                : (ushort*)logp;

    detect_mask<<<1, 64, 0, stream>>>((const uint*)mask, flag);
    linear_kernel<<<256, 256, 0, stream>>>(x, Wi, bi, inp);
    pack_wc<<<128, 256, 0, stream>>>(Wc, Bp);
    att_mfma_kernel<<<(B_ * N_) / 64, 512, 0, stream>>>(context, Bp, bc, V, inp, att);
    softmax_kernel<<<B_, 256, 0, stream>>>(att, mask, flag, alpha, logp);
    wsum_kernel<<<dim3(4, B_), 128, 0, stream>>>(context, alpha, m);
    linear_kernel<<<256, 256, 0, stream>>>(m, Wc, bc, hidden);
}

// Round 11
// 561.635 us; speedup vs baseline: 1.3088x; 1.3088x over previous
//
#include <hip/hip_runtime.h>
#include <hip/hip_bf16.h>
#include <math.h>

#define B_ 128
#define N_ 2048
#define D_ 512
#define H_ 512

#define NEG_BIG (-1.0e30f)

typedef unsigned int uint;
typedef unsigned short ushort;

// ws layout (float offsets)
#define WS_INP  0
#define WS_ATT  (WS_INP + B_*H_)          // 65536
#define WS_M    (WS_ATT + B_*N_)          // +262144
#define WS_FLAG (WS_M + B_*D_)            // +65536
#define WS_BP   393280                    // 16B aligned; Bpack = 524288 ushort = 1MB
#define WS_NEED_FLOATS (WS_BP + 262144)

typedef __attribute__((ext_vector_type(4))) float  f32x4;
typedef __attribute__((ext_vector_type(8))) short  bf16x8;

union BF8 { unsigned short u[8]; bf16x8 v; };

__device__ __forceinline__ ushort f2bf(float x) {
    uint u = __float_as_uint(x);
    u = (u + 0x7fffu + ((u >> 16) & 1u)) >> 16;   // RNE; inputs finite
    return (ushort)u;
}
__device__ __forceinline__ float bf2f(ushort h) {
    return __uint_as_float(((uint)h) << 16);
}
__device__ __forceinline__ float fast_tanh(float x) {
    return 1.0f - 2.0f / (1.0f + __expf(2.0f * x));
}

// ---------------------------------------------------------------------------
__global__ void detect_mask(const uint* __restrict__ mask_raw,
                            int* __restrict__ flag) {
    int lane = threadIdx.x;                 // 64 threads = 1 wave
    uint v = mask_raw[lane];
    unsigned long long m = __ballot(v <= 1u);
    if (lane == 0) *flag = (m == ~0ull) ? 1 : 0;
}

// ---------------------------------------------------------------------------
__global__ __launch_bounds__(256) void linear_kernel(
        const float* __restrict__ a, const float* __restrict__ W,
        const float* __restrict__ bias, float* __restrict__ out) {
    int idx = blockIdx.x * 256 + threadIdx.x;
    int b = idx >> 9;
    int h = idx & (H_ - 1);
    const float4* ar = (const float4*)(a + (size_t)b * D_);
    const float4* wr = (const float4*)(W + (size_t)h * D_);
    float acc = 0.f;
#pragma unroll 4
    for (int d = 0; d < D_ / 4; ++d) {
        float4 av = ar[d], wv = wr[d];
        acc = fmaf(av.x, wv.x, acc);
        acc = fmaf(av.y, wv.y, acc);
        acc = fmaf(av.z, wv.z, acc);
        acc = fmaf(av.w, wv.w, acc);
    }
    out[idx] = acc + bias[h];
}

// ---------------------------------------------------------------------------
// Pre-pack Wc into MFMA B-fragment-linear bf16 hi/lo (RNE).
__global__ __launch_bounds__(256) void pack_wc(const float* __restrict__ Wc,
                                               ushort* __restrict__ Bp) {
    int tid = blockIdx.x * 256 + threadIdx.x;       // 32768 threads
    int lane = tid & 63;
    int fs   = tid >> 6;
    int hf = fs >> 4, ks = fs & 15;
    int h  = hf * 16 + (lane & 15);
    int k0 = ks * 32 + (lane >> 4) * 8;
    const float* src = Wc + (size_t)h * D_ + k0;
    BF8 hi, lo;
#pragma unroll
    for (int j = 0; j < 8; ++j) {
        float x = src[j];
        hi.u[j] = f2bf(x);
        lo.u[j] = f2bf(x - bf2f(hi.u[j]));
    }
    *(bf16x8*)(Bp + (size_t)tid * 8)          = hi.v;
    *(bf16x8*)(Bp + 262144 + (size_t)tid * 8) = lo.v;
}

// ---------------------------------------------------------------------------
// Split-bf16 3-product MFMA, BM=128, full H=512, 512 thr / 8 waves (2r x 4c).
// r8 skeleton + EXPLICIT cluster pipeline: per phase, B ds_reads for cluster
// c+1 are issued (sched_barrier-pinned) before cluster c's MFMAs, so DS-queue
// in-order return + compiler's exact lgkm waits overlap LDS traffic with the
// matrix pipe. Counted vmcnt(10); one raw barrier per phase.
#define KP  32
#define NPH 16

#define DMA_B(p, bi) do {                                                       \
    _Pragma("unroll")                                                           \
    for (int i_ = 0; i_ < 8; ++i_) {                                            \
        int c_  = w * 8 + i_;                                                   \
        int hf_ = c_ & 31;                                                      \
        const ushort* g_ = Bp + (c_ >= 32 ? 262144 : 0)                         \
                         + (size_t)((hf_ << 4) + (p)) * 512 + lane * 8;         \
        ushort* l_ = (c_ >= 32 ? sBl[bi] : sBh[bi]) + hf_ * 512;                \
        __builtin_amdgcn_global_load_lds(                                       \
            (const __attribute__((address_space(1))) unsigned int*)g_,          \
            (__attribute__((address_space(3))) unsigned int*)l_, 16, 0, 0);     \
    }                                                                           \
} while (0)

// truncation split: hi = top16(x); lo = top16(x - bf2f(hi))
#define STAGE_A2(Ux, Wx, bi) do {                                               \
    uint h0_ = (Ux.y & 0xFFFF0000u) | (Ux.x >> 16);                             \
    uint h1_ = (Ux.w & 0xFFFF0000u) | (Ux.z >> 16);                             \
    uint h2_ = (Wx.y & 0xFFFF0000u) | (Wx.x >> 16);                             \
    uint h3_ = (Wx.w & 0xFFFF0000u) | (Wx.z >> 16);                             \
    float r0_ = __uint_as_float(Ux.x) - __uint_as_float(Ux.x & 0xFFFF0000u);    \
    float r1_ = __uint_as_float(Ux.y) - __uint_as_float(Ux.y & 0xFFFF0000u);    \
    float r2_ = __uint_as_float(Ux.z) - __uint_as_float(Ux.z & 0xFFFF0000u);    \
    float r3_ = __uint_as_float(Ux.w) - __uint_as_float(Ux.w & 0xFFFF0000u);    \
    float r4_ = __uint_as_float(Wx.x) - __uint_as_float(Wx.x & 0xFFFF0000u);    \
    float r5_ = __uint_as_float(Wx.y) - __uint_as_float(Wx.y & 0xFFFF0000u);    \
    float r6_ = __uint_as_float(Wx.z) - __uint_as_float(Wx.z & 0xFFFF0000u);    \
    float r7_ = __uint_as_float(Wx.w) - __uint_as_float(Wx.w & 0xFFFF0000u);    \
    uint l0_ = (__float_as_uint(r1_) & 0xFFFF0000u) | (__float_as_uint(r0_) >> 16); \
    uint l1_ = (__float_as_uint(r3_) & 0xFFFF0000u) | (__float_as_uint(r2_) >> 16); \
    uint l2_ = (__float_as_uint(r5_) & 0xFFFF0000u) | (__float_as_uint(r4_) >> 16); \
    uint l3_ = (__float_as_uint(r7_) & 0xFFFF0000u) | (__float_as_uint(r6_) >> 16); \
    *(uint4*)((char*)sAh[bi] + aw) = make_uint4(h0_, h1_, h2_, h3_);            \
    *(uint4*)((char*)sAl[bi] + aw) = make_uint4(l0_, l1_, l2_, l3_);            \
} while (0)

#define MM(a_, b_, c_) __builtin_amdgcn_mfma_f32_16x16x32_bf16(a_, b_, c_, 0, 0, 0)

// one cf column: 12 MFMAs (3 products x 4 row-frags), dep distance 4
#define CL1(c_, BH, BL) do {                                                    \
    acc[0][c_] = MM(ah0, BH, acc[0][c_]); acc[1][c_] = MM(ah1, BH, acc[1][c_]); \
    acc[2][c_] = MM(ah2, BH, acc[2][c_]); acc[3][c_] = MM(ah3, BH, acc[3][c_]); \
    acc[0][c_] = MM(ah0, BL, acc[0][c_]); acc[1][c_] = MM(ah1, BL, acc[1][c_]); \
    acc[2][c_] = MM(ah2, BL, acc[2][c_]); acc[3][c_] = MM(ah3, BL, acc[3][c_]); \
    acc[0][c_] = MM(al0, BH, acc[0][c_]); acc[1][c_] = MM(al1, BH, acc[1][c_]); \
    acc[2][c_] = MM(al2, BH, acc[2][c_]); acc[3][c_] = MM(al3, BH, acc[3][c_]); \
} while (0)

#define LOADB(cf_, BH, BL) do {                                                 \
    const int bo_ = (wc * 8 + (cf_)) * 512 + lane * 8;                          \
    BH = *(const bf16x8*)&sBh[buf][bo_];                                        \
    BL = *(const bf16x8*)&sBl[buf][bo_];                                        \
} while (0)

#define SB0 __builtin_amdgcn_sched_barrier(0)

__global__ __launch_bounds__(512, 2) void att_mfma_kernel(
        const float* __restrict__ ctx, const ushort* __restrict__ Bp,
        const float* __restrict__ bc, const float* __restrict__ V,
        const float* __restrict__ inp, float* __restrict__ att) {
    __shared__ ushort sAh[2][4096];    // 16KB  [buf][rowfrag8][lane64][8]
    __shared__ ushort sAl[2][4096];    // 16KB
    __shared__ ushort sBh[2][16384];   // 64KB  [buf][hf32][lane64][8]
    __shared__ ushort sBl[2][16384];   // 64KB

    const int t    = threadIdx.x;
    const int lane = t & 63;
    const int w    = t >> 6;
    const int wr   = w >> 2;               // row half (64 rows)
    const int wc   = w & 3;                // col group (128 cols)
    const int g0   = blockIdx.x * 128;
    const int b    = g0 >> 11;             // uniform per block

    // A staging geometry (XOR-swizzled)
    const int srow = t >> 2;
    const int skc  = t & 3;
    const float* gAs = ctx + (size_t)(g0 + srow) * D_ + skc * 8;
    unsigned aw = ((unsigned)(srow >> 4) << 10) | ((unsigned)skc << 8)
                | ((unsigned)(srow & 15) << 4);
    aw ^= ((aw >> 8) & 3u) << 4;

    // A fragment read offsets (bytes), same swizzle
    unsigned ar_[4];
#pragma unroll
    for (int rf = 0; rf < 4; ++rf) {
        unsigned o = ((unsigned)(wr * 4 + rf) << 10) | ((unsigned)lane << 4);
        o ^= ((o >> 8) & 3u) << 4;
        ar_[rf] = o;
    }

    f32x4 acc[4][8] = {};

    // prologue
    {
        uint4 U0 = *(const uint4*)(gAs);
        uint4 W0 = *(const uint4*)(gAs + 4);
        SB0;
        DMA_B(0, 0);
        SB0;
        STAGE_A2(U0, W0, 0);               // reg-dep waits A loads (vmcnt(8))
        asm volatile("s_waitcnt lgkmcnt(0)" ::: "memory");
        __builtin_amdgcn_s_barrier();
    }

    for (int p = 0; p < NPH; ++p) {
        const int buf = p & 1;
        const int pn  = (p + 1) & 15;      // uniform; last prefetch dead

        // prefetch next A + DMA next B
        uint4 U  = *(const uint4*)(gAs + pn * KP);
        uint4 Wv = *(const uint4*)(gAs + pn * KP + 4);
        SB0;
        DMA_B(pn, buf ^ 1);
        SB0;
        asm volatile("s_waitcnt vmcnt(10)" ::: "memory");   // prev DMA done
        SB0;

        // R1: A frags + B clusters 0,1
        bf16x8 ah0, al0, ah1, al1, ah2, al2, ah3, al3;
        ah0 = *(const bf16x8*)((const char*)sAh[buf] + ar_[0]);
        al0 = *(const bf16x8*)((const char*)sAl[buf] + ar_[0]);
        ah1 = *(const bf16x8*)((const char*)sAh[buf] + ar_[1]);
        al1 = *(const bf16x8*)((const char*)sAl[buf] + ar_[1]);
        ah2 = *(const bf16x8*)((const char*)sAh[buf] + ar_[2]);
        al2 = *(const bf16x8*)((const char*)sAl[buf] + ar_[2]);
        ah3 = *(const bf16x8*)((const char*)sAh[buf] + ar_[3]);
        al3 = *(const bf16x8*)((const char*)sAl[buf] + ar_[3]);
        bf16x8 bh0, bl0, bh1, bl1;
        LOADB(0, bh0, bl0); LOADB(1, bh1, bl1);
        SB0;
        bf16x8 bh2, bl2, bh3, bl3;
        LOADB(2, bh2, bl2); LOADB(3, bh3, bl3);
        SB0;
        __builtin_amdgcn_s_setprio(1);
        CL1(0, bh0, bl0); CL1(1, bh1, bl1);      // waits A+B0/1 only
        SB0;
        bf16x8 bh4, bl4, bh5, bl5;
        LOADB(4, bh4, bl4); LOADB(5, bh5, bl5);
        SB0;
        CL1(2, bh2, bl2); CL1(3, bh3, bl3);
        SB0;
        bf16x8 bh6, bl6, bh7, bl7;
        LOADB(6, bh6, bl6); LOADB(7, bh7, bl7);
        SB0;
        CL1(4, bh4, bl4); CL1(5, bh5, bl5);
        SB0;
        CL1(6, bh6, bl6); CL1(7, bh7, bl7);
        __builtin_amdgcn_s_setprio(0);
        SB0;

        STAGE_A2(U, Wv, buf ^ 1);          // stage next A (dbuf)
        asm volatile("s_waitcnt lgkmcnt(0)" ::: "memory");
        __builtin_amdgcn_s_barrier();       // raw barrier: no vmem drain
    }

    // epilogue: tanh + V-weight + reduce.  C/D: col=lane&15, row=(lane>>4)*4+j
    float P[4][4] = {};
#pragma unroll
    for (int cf = 0; cf < 8; ++cf) {
        const int h = wc * 128 + cf * 16 + (lane & 15);
        const float sh = inp[b * H_ + h] + bc[h];
        const float vh = V[h];
#pragma unroll
        for (int rf = 0; rf < 4; ++rf)
#pragma unroll
            for (int j = 0; j < 4; ++j)
                P[rf][j] += vh * fast_tanh(acc[rf][cf][j] + sh);
    }
#pragma unroll
    for (int rf = 0; rf < 4; ++rf)
#pragma unroll
        for (int j = 0; j < 4; ++j) {
            float x = P[rf][j];
            x += __shfl_xor(x, 1); x += __shfl_xor(x, 2);
            x += __shfl_xor(x, 4); x += __shfl_xor(x, 8);
            P[rf][j] = x;
        }

    float (*red)[64] = (float(*)[64])sAh;   // overlay (A no longer read)
    if ((lane & 15) == 0) {
        const int kc = lane >> 4;
#pragma unroll
        for (int rf = 0; rf < 4; ++rf)
#pragma unroll
            for (int j = 0; j < 4; ++j)
                red[w][rf * 16 + kc * 4 + j] = P[rf][j];
    }
    __syncthreads();
    if (t < 128) {
        const int wrr = (t >> 6) * 4, r = t & 63;
        att[g0 + t] = red[wrr + 0][r] + red[wrr + 1][r] + red[wrr + 2][r] + red[wrr + 3][r];
    }
}

// ---------------------------------------------------------------------------
__global__ __launch_bounds__(256) void softmax_kernel(
        const float* __restrict__ att, const void* __restrict__ mask,
        const int* __restrict__ flag, float* __restrict__ alpha,
        float* __restrict__ logp) {
    __shared__ float row[N_];
    __shared__ float red[4];
    const int b = blockIdx.x, t = threadIdx.x;
    const int is_int = *flag;
    const int* mi = (const int*)mask;
    const unsigned char* mb = (const unsigned char*)mask;

    float lmax = -INFINITY;
    for (int n = t; n < N_; n += 256) {
        bool m = is_int ? (mi[b * N_ + n] != 0) : (mb[b * N_ + n] != 0);
        float a = m ? NEG_BIG : att[b * N_ + n];
        row[n] = a;
        lmax = fmaxf(lmax, a);
    }
#pragma unroll
    for (int off = 32; off; off >>= 1) lmax = fmaxf(lmax, __shfl_down(lmax, off));
    if ((t & 63) == 0) red[t >> 6] = lmax;
    __syncthreads();
    const float rmax = fmaxf(fmaxf(red[0], red[1]), fmaxf(red[2], red[3]));
    __syncthreads();

    float lsum = 0.f;
    for (int n = t; n < N_; n += 256) lsum += __expf(row[n] - rmax);
#pragma unroll
    for (int off = 32; off; off >>= 1) lsum += __shfl_down(lsum, off);
    if ((t & 63) == 0) red[t >> 6] = lsum;
    __syncthreads();
    const float s = red[0] + red[1] + red[2] + red[3];
    const float inv = 1.0f / s;
    const float lse = logf(s);

    for (int n = t; n < N_; n += 256) {
        float a = row[n];
        alpha[b * N_ + n] = __expf(a - rmax) * inv;
        logp[b * N_ + n]  = a - rmax - lse;
    }
}

// ---------------------------------------------------------------------------
// m[b][d] = sum_n alpha[b][n]*ctx[b][n][d]; 512 thr: 4-way n-split per col.
__global__ __launch_bounds__(512) void wsum_kernel(
        const float* __restrict__ context, const float* __restrict__ alpha,
        float* __restrict__ m) {
    __shared__ float al[N_];
    __shared__ float part[3][128];
    const int c = blockIdx.x;          // d chunk (128 cols)
    const int b = blockIdx.y;
    const int t = threadIdx.x;
    for (int n = t; n < N_; n += 512) al[n] = alpha[(size_t)b * N_ + n];
    __syncthreads();
    const int d = c * 128 + (t & 127);
    const int q = t >> 7;              // n quarter
    const float* cp = context + (size_t)b * N_ * D_ + (size_t)q * 512 * D_ + d;
    const float* ap = al + q * 512;
    float acc = 0.f;
#pragma unroll 8
    for (int n = 0; n < 512; ++n) acc = fmaf(ap[n], cp[(size_t)n * D_], acc);
    if (q) part[q - 1][t & 127] = acc;
    __syncthreads();
    if (q == 0)
        m[b * D_ + d] = acc + part[0][t & 127] + part[1][t & 127] + part[2][t & 127];
}

// ---------------------------------------------------------------------------
extern "C" void kernel_launch(void* const* d_in, const int* in_sizes, int n_in,
                              void* d_out, int out_size, void* d_ws, size_t ws_size,
                              hipStream_t stream) {
    const float* x       = (const float*)d_in[0];
    const float* context = (const float*)d_in[1];
    const void*  mask    = d_in[2];
    const float* Wi      = (const float*)d_in[3];
    const float* bi      = (const float*)d_in[4];
    const float* Wc      = (const float*)d_in[5];
    const float* bc      = (const float*)d_in[6];
    const float* V       = (const float*)d_in[7];

    float* out  = (float*)d_out;
    float* ws   = (float*)d_ws;
    float* inp  = ws + WS_INP;
    float* att  = ws + WS_ATT;
    float* m    = ws + WS_M;
    int*   flag = (int*)(ws + WS_FLAG);

    float* hidden = out;
    float* alpha  = out + B_ * H_;
    float* logp   = alpha + B_ * N_;

    ushort* Bp =
        (ws_size >= (size_t)WS_NEED_FLOATS * 4) ? (ushort*)(ws + WS_BP)
                                                : (ushort*)logp;

    detect_mask<<<1, 64, 0, stream>>>((const uint*)mask, flag);
    linear_kernel<<<256, 256, 0, stream>>>(x, Wi, bi, inp);
    pack_wc<<<128, 256, 0, stream>>>(Wc, Bp);
    att_mfma_kernel<<<(B_ * N_) / 128, 512, 0, stream>>>(context, Bp, bc, V, inp, att);
    softmax_kernel<<<B_, 256, 0, stream>>>(att, mask, flag, alpha, logp);
    wsum_kernel<<<dim3(4, B_), 512, 0, stream>>>(context, alpha, m);
    linear_kernel<<<256, 256, 0, stream>>>(m, Wc, bc, hidden);
}